// Round 1
// baseline (14491.011 us; speedup 1.0000x reference)
//
#include <hip/hip_runtime.h>
#include <cstdint>
#include <cstddef>

#define Dk 256
#define Hk 512
#define Bk 16
#define Tk 512
#define Gk 2048      // 4H
#define NVk 262144   // H*H
#define NBLK 512

typedef __bf16 bf16;
typedef __bf16 bf16x8 __attribute__((ext_vector_type(8)));
typedef float  f32x4  __attribute__((ext_vector_type(4)));
typedef const __attribute__((address_space(1))) void* gvp;
typedef __attribute__((address_space(3))) void* lvp;

__device__ __forceinline__ float bflo(unsigned u) {
  u <<= 16; return __builtin_bit_cast(float, u);
}
__device__ __forceinline__ float bfhi(unsigned u) {
  u &= 0xffff0000u; return __builtin_bit_cast(float, u);
}

// ---------- prep kernels ----------
__global__ __launch_bounds__(256) void cvt_f32_bf16(const float* __restrict__ in,
                                                    bf16* __restrict__ out, int n8) {
  int i = blockIdx.x * 256 + threadIdx.x;
  if (i >= n8) return;
  const float4* p = reinterpret_cast<const float4*>(in) + (size_t)i * 2;
  float4 a = p[0], b = p[1];
  bf16x8 v;
  v[0] = (bf16)a.x; v[1] = (bf16)a.y; v[2] = (bf16)a.z; v[3] = (bf16)a.w;
  v[4] = (bf16)b.x; v[5] = (bf16)b.y; v[6] = (bf16)b.z; v[7] = (bf16)b.w;
  *reinterpret_cast<bf16x8*>(out + (size_t)i * 8) = v;
}

// V_w[j][d*512+h'] (fp32) -> packed B: V2p[(d/8)][n=(j,h')][d%8] (bf16)
__global__ __launch_bounds__(256) void pack_V(const float* __restrict__ Vw,
                                              bf16* __restrict__ V2p) {
  int n = blockIdx.x * 256 + threadIdx.x;        // 0..262143
  int j = n >> 9, hp = n & 511;
  const float* src = Vw + (size_t)j * 131072 + hp;
  for (int kb = 0; kb < 32; ++kb) {
    bf16x8 v;
#pragma unroll
    for (int r = 0; r < 8; ++r) v[r] = (bf16)src[(size_t)(kb * 8 + r) * 512];
    *reinterpret_cast<bf16x8*>(V2p + ((size_t)kb * NVk + n) * 8) = v;
  }
}

// W_w[g][d] (fp32) -> packed B: Wp[(d/8)][g][d%8] (bf16)
__global__ __launch_bounds__(256) void pack_W(const float* __restrict__ Ww,
                                              bf16* __restrict__ Wp) {
  int g = blockIdx.x * 256 + threadIdx.x;        // 0..2047
  const float* src = Ww + (size_t)g * 256;
  for (int kb = 0; kb < 32; ++kb) {
    bf16x8 v;
#pragma unroll
    for (int r = 0; r < 8; ++r) v[r] = (bf16)src[kb * 8 + r];
    *reinterpret_cast<bf16x8*>(Wp + ((size_t)kb * Gk + g) * 8) = v;
  }
}

// x[row][d] (fp32, row=b*512+t) -> packed A: xp[(d/8)][row][d%8] (bf16)
__global__ __launch_bounds__(256) void pack_x(const float* __restrict__ x,
                                              bf16* __restrict__ xp) {
  int row = blockIdx.x * 256 + threadIdx.x;      // 0..8191
  const float* src = x + (size_t)row * 256;
  for (int kb = 0; kb < 32; ++kb) {
    bf16x8 v;
#pragma unroll
    for (int r = 0; r < 8; ++r) v[r] = (bf16)src[kb * 8 + r];
    *reinterpret_cast<bf16x8*>(xp + ((size_t)kb * 8192 + row) * 8) = v;
  }
}

__global__ __launch_bounds__(256) void init_state(bf16* __restrict__ hbuf,
                                                  float* __restrict__ cws,
                                                  int* __restrict__ bar) {
  int i = blockIdx.x * 256 + threadIdx.x;
  if (i < 16384) hbuf[i] = (bf16)0.f;
  if (i < 8192)  cws[i]  = 0.f;
  if (i < 256)   bar[i]  = 0;
}

// ---------- 128x128 tile MFMA GEMM with global_load_lds staging ----------
template <bool BF16_OUT>
__global__ __launch_bounds__(256) void gemm128(const bf16* __restrict__ Ap,
                                               const bf16* __restrict__ Bp,
                                               float* __restrict__ outF,
                                               bf16* __restrict__ outB,
                                               const float* __restrict__ bias,
                                               const float* __restrict__ bias2,
                                               int N, int Mtot,
                                               int t0, int tcMask, int tcShift) {
  __shared__ uint4 a_sm[512];   // [kb(4)][m(128)] 16B each
  __shared__ uint4 b_sm[512];   // [kb(4)][n(128)]
  int tid = threadIdx.x;
  int lane = tid & 63, w = tid >> 6;
  int quad = lane >> 4, l15 = lane & 15;
  int wm = w >> 1, wn = w & 1;
  int m0 = blockIdx.x * 128, n0 = blockIdx.y * 128;

  f32x4 acc[4][4];
#pragma unroll
  for (int i = 0; i < 4; ++i)
#pragma unroll
    for (int j = 0; j < 4; ++j) acc[i][j] = (f32x4){0.f, 0.f, 0.f, 0.f};

  int gm0 = m0 + lane, gm1 = m0 + 64 + lane;
  int xr0 = ((gm0 >> tcShift) << 9) + t0 + (gm0 & tcMask);
  int xr1 = ((gm1 >> tcShift) << 9) + t0 + (gm1 & tcMask);
  const uint4* gA = reinterpret_cast<const uint4*>(Ap);
  const uint4* gB = reinterpret_cast<const uint4*>(Bp);

  const bf16x8* aptr = reinterpret_cast<const bf16x8*>(a_sm);
  const bf16x8* bptr = reinterpret_cast<const bf16x8*>(b_sm);

  for (int kk = 0; kk < 8; ++kk) {
    size_t kbg = (size_t)(kk * 4 + w);
    __builtin_amdgcn_global_load_lds((gvp)(gA + kbg * Mtot + xr0),
                                     (lvp)(&a_sm[w * 128]), 16, 0, 0);
    __builtin_amdgcn_global_load_lds((gvp)(gA + kbg * Mtot + xr1),
                                     (lvp)(&a_sm[w * 128 + 64]), 16, 0, 0);
    __builtin_amdgcn_global_load_lds((gvp)(gB + kbg * N + n0 + lane),
                                     (lvp)(&b_sm[w * 128]), 16, 0, 0);
    __builtin_amdgcn_global_load_lds((gvp)(gB + kbg * N + n0 + 64 + lane),
                                     (lvp)(&b_sm[w * 128 + 64]), 16, 0, 0);
    __syncthreads();
    bf16x8 af[4], bfr[4];
#pragma unroll
    for (int i = 0; i < 4; ++i) af[i]  = aptr[quad * 128 + wm * 64 + i * 16 + l15];
#pragma unroll
    for (int j = 0; j < 4; ++j) bfr[j] = bptr[quad * 128 + wn * 64 + j * 16 + l15];
#pragma unroll
    for (int i = 0; i < 4; ++i)
#pragma unroll
      for (int j = 0; j < 4; ++j)
        acc[i][j] = __builtin_amdgcn_mfma_f32_16x16x32_bf16(af[i], bfr[j], acc[i][j], 0, 0, 0);
    __syncthreads();
  }

#pragma unroll
  for (int i = 0; i < 4; ++i) {
    int row = m0 + wm * 64 + i * 16 + quad * 4;
#pragma unroll
    for (int j = 0; j < 4; ++j) {
      int col = n0 + wn * 64 + j * 16 + l15;
      f32x4 v = acc[i][j];
      if (BF16_OUT) {
#pragma unroll
        for (int r = 0; r < 4; ++r)
          outB[(size_t)(row + r) * N + col] = (bf16)v[r];
      } else {
        float bv = bias[col] + bias2[col];
#pragma unroll
        for (int r = 0; r < 4; ++r)
          outF[(size_t)(row + r) * N + col] = v[r] + bv;
      }
    }
  }
}

// ---------- per-step scan kernel (fallback path only) ----------
__global__ __launch_bounds__(256) void scan_step3(
    const bf16* __restrict__ A, int trel, int Tc,
    const bf16* __restrict__ Ubf, const float* __restrict__ wx,
    const float* __restrict__ Vb,
    const bf16* __restrict__ hprev, bf16* __restrict__ hnext,
    float* __restrict__ cst, float* __restrict__ out, int t) {
  __shared__ bf16 U_s[4 * Hk];
  __shared__ float gate_s[64];
  __shared__ float m_s[16];
  int tid = threadIdx.x;
  int j = blockIdx.x;
  int b = tid >> 4, sm = tid & 15;

  const bf16* Ar = A + ((size_t)b * Tc + trel) * NVk + (size_t)j * Hk;
  uint4 av[4];
#pragma unroll
  for (int i = 0; i < 4; ++i)
    av[i] = *reinterpret_cast<const uint4*>(Ar + i * 128 + sm * 8);

  uint4 hv[4];
#pragma unroll
  for (int i = 0; i < 4; ++i)
    hv[i] = *reinterpret_cast<const uint4*>(hprev + b * Hk + i * 128 + sm * 8);

  {
    int r = tid >> 6, e = (tid & 63) * 8;
    *reinterpret_cast<uint4*>(U_s + r * Hk + e) =
        *reinterpret_cast<const uint4*>(Ubf + ((size_t)r * Hk + j) * Hk + e);
  }
  __syncthreads();

  float hf[4][8];
#pragma unroll
  for (int i = 0; i < 4; ++i) {
    unsigned ux = hv[i].x, uy = hv[i].y, uz = hv[i].z, uw = hv[i].w;
    hf[i][0] = bflo(ux); hf[i][1] = bfhi(ux);
    hf[i][2] = bflo(uy); hf[i][3] = bfhi(uy);
    hf[i][4] = bflo(uz); hf[i][5] = bfhi(uz);
    hf[i][6] = bflo(uw); hf[i][7] = bfhi(uw);
  }

  float accs[5] = {0.f, 0.f, 0.f, 0.f, 0.f};
  const uint4* Uq = reinterpret_cast<const uint4*>(U_s);
#pragma unroll
  for (int i = 0; i < 4; ++i) {
#pragma unroll
    for (int q = 0; q < 4; ++q) {
      uint4 u = Uq[q * 64 + i * 16 + sm];
      accs[q] += bflo(u.x) * hf[i][0] + bfhi(u.x) * hf[i][1]
               + bflo(u.y) * hf[i][2] + bfhi(u.y) * hf[i][3]
               + bflo(u.z) * hf[i][4] + bfhi(u.z) * hf[i][5]
               + bflo(u.w) * hf[i][6] + bfhi(u.w) * hf[i][7];
    }
    uint4 a = av[i];
    accs[4] += bflo(a.x) * hf[i][0] + bfhi(a.x) * hf[i][1]
             + bflo(a.y) * hf[i][2] + bfhi(a.y) * hf[i][3]
             + bflo(a.z) * hf[i][4] + bfhi(a.z) * hf[i][5]
             + bflo(a.w) * hf[i][6] + bfhi(a.w) * hf[i][7];
  }
#pragma unroll
  for (int d = 1; d < 16; d <<= 1) {
#pragma unroll
    for (int k = 0; k < 5; ++k) accs[k] += __shfl_xor(accs[k], d);
  }
  if (sm == 0) {
    const float* wxr = wx + ((size_t)b * Tk + t) * Gk + j;
#pragma unroll
    for (int q = 0; q < 4; ++q) gate_s[q * 16 + b] = accs[q] + wxr[q * Hk];
    m_s[b] = accs[4];
  }
  __syncthreads();

  if (tid < 16) {
    int bb = tid;
    float gi = gate_s[bb], gf = gate_s[16 + bb];
    float go = gate_s[32 + bb], gg = gate_s[48 + bb];
    float iv = 1.f / (1.f + __expf(-gi));
    float fv = 1.f / (1.f + __expf(-gf));
    float ov = 1.f / (1.f + __expf(-go));
    float gv = tanhf(gg);
    float mv = tanhf(m_s[bb] + Vb[j]);
    int idx = bb * Hk + j;
    float c = fv * cst[idx] + iv * gv + 0.1f * mv;
    cst[idx] = c;
    float h = ov * tanhf(c);
    hnext[idx] = (bf16)h;
    out[((size_t)bb * Tk + t) * Hk + j] = h;
    if (t == Tk - 1) {
      out[(size_t)Bk * Tk * Hk + idx] = h;
      out[(size_t)Bk * Tk * Hk + Bk * Hk + idx] = c;
    }
  }
}

// ---------- two-level grid barrier for 512 blocks (8 groups x 64) ----------
// bar layout (ints): cnt1 at 0,16,..,112 (one cacheline apart); cnt2 at 160; gen at 192.
__device__ __forceinline__ void gbar512(int* bar) {
  __syncthreads();   // all threads' prior stores drained to L2 before arrival
  if (threadIdx.x == 0) {
    int g = __hip_atomic_load(bar + 192, __ATOMIC_RELAXED, __HIP_MEMORY_SCOPE_AGENT);
    int grp = (int)blockIdx.x >> 6;
    int a = __hip_atomic_fetch_add(bar + grp * 16, 1, __ATOMIC_ACQ_REL,
                                   __HIP_MEMORY_SCOPE_AGENT);
    if (a == 63) {
      __hip_atomic_store(bar + grp * 16, 0, __ATOMIC_RELAXED, __HIP_MEMORY_SCOPE_AGENT);
      int b2 = __hip_atomic_fetch_add(bar + 160, 1, __ATOMIC_ACQ_REL,
                                      __HIP_MEMORY_SCOPE_AGENT);
      if (b2 == 7) {
        __hip_atomic_store(bar + 160, 0, __ATOMIC_RELAXED, __HIP_MEMORY_SCOPE_AGENT);
        __hip_atomic_store(bar + 192, g + 1, __ATOMIC_RELEASE, __HIP_MEMORY_SCOPE_AGENT);
      }
    }
    while (__hip_atomic_load(bar + 192, __ATOMIC_RELAXED, __HIP_MEMORY_SCOPE_AGENT) == g)
      __builtin_amdgcn_s_sleep(1);
    (void)__hip_atomic_load(bar + 192, __ATOMIC_ACQUIRE, __HIP_MEMORY_SCOPE_AGENT);
  }
  __syncthreads();
}

// ---------- persistent cooperative scan: one launch per time-chunk ----------
// 512 blocks (one j each, 2 blocks/CU) x 256 threads. U staged to LDS once,
// c held in registers, A[t+1] prefetched to regs before the inter-step barrier.
__global__ __launch_bounds__(256, 2) void scan_persist(
    const bf16* __restrict__ A, int Tc, int c0,
    const bf16* __restrict__ Ubf, const float* __restrict__ wx,
    const float* __restrict__ Vb, bf16* __restrict__ hbuf,
    float* __restrict__ cst, float* __restrict__ out, int* __restrict__ bar) {
  __shared__ bf16 U_s[4 * Hk];      // 4 KB, persistent for the whole chunk
  __shared__ float gate_s[64];
  __shared__ float m_s[16];
  int tid = threadIdx.x;
  int j = blockIdx.x;
  int b = tid >> 4, sm = tid & 15;

  {
    int r = tid >> 6, e = (tid & 63) * 8;
    *reinterpret_cast<uint4*>(U_s + r * Hk + e) =
        *reinterpret_cast<const uint4*>(Ubf + ((size_t)r * Hk + j) * Hk + e);
  }
  float c_reg = (tid < 16) ? cst[tid * Hk + j] : 0.f;
  float vb = Vb[j];
  __syncthreads();

  const uint4* Aq = reinterpret_cast<const uint4*>(A);
  const uint4* Uq = reinterpret_cast<const uint4*>(U_s);
  size_t abase = (size_t)(b * Tc) * 32768 + (size_t)j * 64 + sm;

  uint4 avA[4], avB[4];
#pragma unroll
  for (int i = 0; i < 4; ++i) avA[i] = Aq[abase + i * 16];

  for (int trel = 0; trel < Tc; ++trel) {
    int t = c0 + trel;
    const bf16* hprev = hbuf + (t & 1) * 8192;
    bf16* hnext = hbuf + ((t + 1) & 1) * 8192;

    // h broadcast read (visible: barrier at bottom of previous iteration)
    uint4 hv[4];
#pragma unroll
    for (int i = 0; i < 4; ++i)
      hv[i] = *reinterpret_cast<const uint4*>(hprev + b * Hk + i * 128 + sm * 8);

    // issue wx gate loads early; latency hides under the MAC loop
    float wxq[4] = {0.f, 0.f, 0.f, 0.f};
    if (sm == 0) {
      const float* wxr = wx + ((size_t)b * Tk + t) * Gk + j;
#pragma unroll
      for (int q = 0; q < 4; ++q) wxq[q] = wxr[q * Hk];
    }

    float accs[5] = {0.f, 0.f, 0.f, 0.f, 0.f};
#pragma unroll
    for (int i = 0; i < 4; ++i) {
      float hf[8];
      unsigned ux = hv[i].x, uy = hv[i].y, uz = hv[i].z, uw = hv[i].w;
      hf[0] = bflo(ux); hf[1] = bfhi(ux);
      hf[2] = bflo(uy); hf[3] = bfhi(uy);
      hf[4] = bflo(uz); hf[5] = bfhi(uz);
      hf[6] = bflo(uw); hf[7] = bfhi(uw);
#pragma unroll
      for (int q = 0; q < 4; ++q) {
        uint4 u = Uq[q * 64 + i * 16 + sm];
        accs[q] += bflo(u.x) * hf[0] + bfhi(u.x) * hf[1]
                 + bflo(u.y) * hf[2] + bfhi(u.y) * hf[3]
                 + bflo(u.z) * hf[4] + bfhi(u.z) * hf[5]
                 + bflo(u.w) * hf[6] + bfhi(u.w) * hf[7];
      }
      uint4 a = avA[i];
      accs[4] += bflo(a.x) * hf[0] + bfhi(a.x) * hf[1]
               + bflo(a.y) * hf[2] + bfhi(a.y) * hf[3]
               + bflo(a.z) * hf[4] + bfhi(a.z) * hf[5]
               + bflo(a.w) * hf[6] + bfhi(a.w) * hf[7];
    }

    // prefetch A[t+1]: issued pre-barrier, drains during barrier arrival
    if (trel + 1 < Tc) {
      size_t nb = abase + (size_t)(trel + 1) * 32768;
#pragma unroll
      for (int i = 0; i < 4; ++i) avB[i] = Aq[nb + i * 16];
    }

#pragma unroll
    for (int d = 1; d < 16; d <<= 1) {
#pragma unroll
      for (int k = 0; k < 5; ++k) accs[k] += __shfl_xor(accs[k], d);
    }
    if (sm == 0) {
#pragma unroll
      for (int q = 0; q < 4; ++q) gate_s[q * 16 + b] = accs[q] + wxq[q];
      m_s[b] = accs[4];
    }
    __syncthreads();

    if (tid < 16) {
      float gi = gate_s[tid], gf = gate_s[16 + tid];
      float go = gate_s[32 + tid], gg = gate_s[48 + tid];
      float iv = 1.f / (1.f + __expf(-gi));
      float fv = 1.f / (1.f + __expf(-gf));
      float ov = 1.f / (1.f + __expf(-go));
      float gv = tanhf(gg);
      float mv = tanhf(m_s[tid] + vb);
      float c = fv * c_reg + iv * gv + 0.1f * mv;
      c_reg = c;
      float h = ov * tanhf(c);
      hnext[tid * Hk + j] = (bf16)h;
      out[((size_t)tid * Tk + t) * Hk + j] = h;
      if (t == Tk - 1) {
        out[(size_t)Bk * Tk * Hk + tid * Hk + j] = h;                 // hT
        out[(size_t)Bk * Tk * Hk + Bk * Hk + tid * Hk + j] = c;       // cT
      }
    }

    gbar512(bar);

#pragma unroll
    for (int i = 0; i < 4; ++i) avA[i] = avB[i];
  }
  if (tid < 16) cst[tid * Hk + j] = c_reg;
}

// ---------- host ----------
extern "C" void kernel_launch(void* const* d_in, const int* in_sizes, int n_in,
                              void* d_out, int out_size, void* d_ws, size_t ws_size,
                              hipStream_t stream) {
  const float* x  = (const float*)d_in[0];
  const float* Ww = (const float*)d_in[1];
  const float* Wb = (const float*)d_in[2];
  const float* Uw = (const float*)d_in[3];
  const float* Ub = (const float*)d_in[4];
  const float* Vw = (const float*)d_in[5];
  const float* Vb = (const float*)d_in[6];
  float* out = (float*)d_out;

  char* ws = (char*)d_ws;
  size_t off = 0;
  auto alloc = [&](size_t bytes) -> void* {
    void* p = ws + off;
    off = (off + bytes + 255) & ~(size_t)255;
    return p;
  };
  bf16*  xp   = (bf16*)alloc((size_t)Bk * Tk * Dk * 2);   //   4 MB packed x
  bf16*  V2p  = (bf16*)alloc((size_t)32 * NVk * 8 * 2);   // 134 MB
  bf16*  Wp   = (bf16*)alloc((size_t)32 * Gk * 8 * 2);    //   1 MB
  bf16*  Ubf  = (bf16*)alloc((size_t)Gk * Hk * 2);        //   2 MB
  float* wx   = (float*)alloc((size_t)Bk * Tk * Gk * 4);  //  67 MB
  bf16*  hbuf = (bf16*)alloc((size_t)16384 * 2);          // double buffer, bf16
  float* cws  = (float*)alloc((size_t)8192 * 4);
  int*   bar  = (int*)alloc(256 * sizeof(int));           // grid barrier state
  size_t fixedBytes = off;

  int Tc = 512;   // time-chunk for A; shrink until it fits the workspace
  while (Tc > 8 && fixedBytes + (size_t)Bk * Tc * Hk * Hk * 2 > ws_size) Tc >>= 1;
  bf16* A_ws = (bf16*)alloc((size_t)Bk * Tc * Hk * Hk * 2);
  int tcShift = 31 - __builtin_clz((unsigned)Tc);

  pack_x<<<32, 256, 0, stream>>>(x, xp);
  cvt_f32_bf16<<<512, 256, 0, stream>>>(Uw, Ubf, 131072);
  pack_V<<<1024, 256, 0, stream>>>(Vw, V2p);
  pack_W<<<8, 256, 0, stream>>>(Ww, Wp);
  init_state<<<64, 256, 0, stream>>>(hbuf, cws, bar);

  // wx = x @ W^T + (W_b + U_b)   (M=8192, N=2048, K=256), identity row map
  gemm128<false><<<dim3(64, 16), 256, 0, stream>>>(xp, Wp, wx, nullptr, Wb, Ub,
                                                   Gk, 8192, 0, 511, 9);

  for (int c0 = 0; c0 < Tk; c0 += Tc) {
    // A[b, t0..t0+Tc, j, h'] = x(b,t) . V(:,d,:)   (M=16*Tc, N=262144, K=256)
    gemm128<true><<<dim3(Bk * Tc / 128, NVk / 128), 256, 0, stream>>>(
        xp, V2p, nullptr, A_ws, nullptr, nullptr, NVk, 8192, c0, Tc - 1, tcShift);

    int TcV = Tc, c0V = c0;
    void* args[] = {(void*)&A_ws, (void*)&TcV, (void*)&c0V, (void*)&Ubf,
                    (void*)&wx, (void*)&Vb, (void*)&hbuf, (void*)&cws,
                    (void*)&out, (void*)&bar};
    hipError_t e = hipLaunchCooperativeKernel((const void*)scan_persist,
                                              dim3(NBLK), dim3(256), args, 0, stream);
    if (e != hipSuccess) {
      // fallback: per-step launches (previous verified path)
      for (int t = c0; t < c0 + Tc; ++t)
        scan_step3<<<512, 256, 0, stream>>>(
            A_ws, t - c0, Tc, Ubf, wx, Vb,
            hbuf + (t & 1) * 8192, hbuf + ((t + 1) & 1) * 8192,
            cws, out, t);
    }
  }
}

// Round 3
// 6269.387 us; speedup vs baseline: 2.3114x; 2.3114x over previous
//
#include <hip/hip_runtime.h>
#include <cstdint>
#include <cstddef>

#define Dk 256
#define Hk 512
#define Bk 16
#define Tk 512
#define Gk 2048      // 4H
#define NVk 262144   // H*H
#define NBLK 256     // persistent scan blocks (2 j's each)

typedef __bf16 bf16;
typedef __bf16 bf16x8 __attribute__((ext_vector_type(8)));
typedef float  f32x4  __attribute__((ext_vector_type(4)));
typedef const __attribute__((address_space(1))) void* gvp;
typedef __attribute__((address_space(3))) void* lvp;

__device__ __forceinline__ float bflo(unsigned u) {
  u <<= 16; return __builtin_bit_cast(float, u);
}
__device__ __forceinline__ float bfhi(unsigned u) {
  u &= 0xffff0000u; return __builtin_bit_cast(float, u);
}

// relaxed agent-scope atomics -> sc1 accesses at the coherent point; no
// buffer_wbl2 / buffer_inv cache maintenance is ever emitted.
__device__ __forceinline__ int ld_rlx(const int* p) {
  return __hip_atomic_load(p, __ATOMIC_RELAXED, __HIP_MEMORY_SCOPE_AGENT);
}
__device__ __forceinline__ void st_rlx(int* p, int v) {
  __hip_atomic_store(p, v, __ATOMIC_RELAXED, __HIP_MEMORY_SCOPE_AGENT);
}
#define VMWAIT asm volatile("s_waitcnt vmcnt(0)" ::: "memory")

// ---------- prep kernels ----------
__global__ __launch_bounds__(256) void cvt_f32_bf16(const float* __restrict__ in,
                                                    bf16* __restrict__ out, int n8) {
  int i = blockIdx.x * 256 + threadIdx.x;
  if (i >= n8) return;
  const float4* p = reinterpret_cast<const float4*>(in) + (size_t)i * 2;
  float4 a = p[0], b = p[1];
  bf16x8 v;
  v[0] = (bf16)a.x; v[1] = (bf16)a.y; v[2] = (bf16)a.z; v[3] = (bf16)a.w;
  v[4] = (bf16)b.x; v[5] = (bf16)b.y; v[6] = (bf16)b.z; v[7] = (bf16)b.w;
  *reinterpret_cast<bf16x8*>(out + (size_t)i * 8) = v;
}

// V_w[j][d*512+h'] (fp32) -> packed B: V2p[(d/8)][n=(j,h')][d%8] (bf16)
__global__ __launch_bounds__(256) void pack_V(const float* __restrict__ Vw,
                                              bf16* __restrict__ V2p) {
  int n = blockIdx.x * 256 + threadIdx.x;        // 0..262143
  int j = n >> 9, hp = n & 511;
  const float* src = Vw + (size_t)j * 131072 + hp;
  for (int kb = 0; kb < 32; ++kb) {
    bf16x8 v;
#pragma unroll
    for (int r = 0; r < 8; ++r) v[r] = (bf16)src[(size_t)(kb * 8 + r) * 512];
    *reinterpret_cast<bf16x8*>(V2p + ((size_t)kb * NVk + n) * 8) = v;
  }
}

// W_w[g][d] (fp32) -> packed B: Wp[(d/8)][g][d%8] (bf16)
__global__ __launch_bounds__(256) void pack_W(const float* __restrict__ Ww,
                                              bf16* __restrict__ Wp) {
  int g = blockIdx.x * 256 + threadIdx.x;        // 0..2047
  const float* src = Ww + (size_t)g * 256;
  for (int kb = 0; kb < 32; ++kb) {
    bf16x8 v;
#pragma unroll
    for (int r = 0; r < 8; ++r) v[r] = (bf16)src[kb * 8 + r];
    *reinterpret_cast<bf16x8*>(Wp + ((size_t)kb * Gk + g) * 8) = v;
  }
}

// x[row][d] (fp32, row=b*512+t) -> packed A: xp[(d/8)][row][d%8] (bf16)
__global__ __launch_bounds__(256) void pack_x(const float* __restrict__ x,
                                              bf16* __restrict__ xp) {
  int row = blockIdx.x * 256 + threadIdx.x;      // 0..8191
  const float* src = x + (size_t)row * 256;
  for (int kb = 0; kb < 32; ++kb) {
    bf16x8 v;
#pragma unroll
    for (int r = 0; r < 8; ++r) v[r] = (bf16)src[kb * 8 + r];
    *reinterpret_cast<bf16x8*>(xp + ((size_t)kb * 8192 + row) * 8) = v;
  }
}

__global__ __launch_bounds__(256) void init_state(bf16* __restrict__ hbuf,
                                                  float* __restrict__ cws,
                                                  int* __restrict__ bar) {
  int i = blockIdx.x * 256 + threadIdx.x;
  if (i < 16384) hbuf[i] = (bf16)0.f;
  if (i < 8192)  cws[i]  = 0.f;
  if (i < 2048)  bar[i]  = 0;
}

// ---------- 128x128 tile MFMA GEMM with global_load_lds staging ----------
// swzShift >= 0: 1D grid of (mt*2048) blocks, mt = 1<<swzShift m-tiles.
// Same-B-panel blocks get ids congruent mod 8 -> same XCD (round-robin heur).
template <bool BF16_OUT>
__global__ __launch_bounds__(256) void gemm128(const bf16* __restrict__ Ap,
                                               const bf16* __restrict__ Bp,
                                               float* __restrict__ outF,
                                               bf16* __restrict__ outB,
                                               const float* __restrict__ bias,
                                               const float* __restrict__ bias2,
                                               int N, int Mtot,
                                               int t0, int tcMask, int tcShift,
                                               int swzShift) {
  __shared__ uint4 a_sm[512];   // [kb(4)][m(128)] 16B each
  __shared__ uint4 b_sm[512];   // [kb(4)][n(128)]
  int tid = threadIdx.x;
  int lane = tid & 63, w = tid >> 6;
  int quad = lane >> 4, l15 = lane & 15;
  int wm = w >> 1, wn = w & 1;
  int m0, n0;
  if (swzShift >= 0) {
    int id = blockIdx.x;
    int r = id & 7, q = id >> 3;
    m0 = (q & ((1 << swzShift) - 1)) << 7;
    n0 = (r + ((q >> swzShift) << 3)) << 7;
  } else {
    m0 = blockIdx.x << 7; n0 = blockIdx.y << 7;
  }

  f32x4 acc[4][4];
#pragma unroll
  for (int i = 0; i < 4; ++i)
#pragma unroll
    for (int j = 0; j < 4; ++j) acc[i][j] = (f32x4){0.f, 0.f, 0.f, 0.f};

  int gm0 = m0 + lane, gm1 = m0 + 64 + lane;
  int xr0 = ((gm0 >> tcShift) << 9) + t0 + (gm0 & tcMask);
  int xr1 = ((gm1 >> tcShift) << 9) + t0 + (gm1 & tcMask);
  const uint4* gA = reinterpret_cast<const uint4*>(Ap);
  const uint4* gB = reinterpret_cast<const uint4*>(Bp);

  const bf16x8* aptr = reinterpret_cast<const bf16x8*>(a_sm);
  const bf16x8* bptr = reinterpret_cast<const bf16x8*>(b_sm);

  for (int kk = 0; kk < 8; ++kk) {
    size_t kbg = (size_t)(kk * 4 + w);
    __builtin_amdgcn_global_load_lds((gvp)(gA + kbg * Mtot + xr0),
                                     (lvp)(&a_sm[w * 128]), 16, 0, 0);
    __builtin_amdgcn_global_load_lds((gvp)(gA + kbg * Mtot + xr1),
                                     (lvp)(&a_sm[w * 128 + 64]), 16, 0, 0);
    __builtin_amdgcn_global_load_lds((gvp)(gB + kbg * N + n0 + lane),
                                     (lvp)(&b_sm[w * 128]), 16, 0, 0);
    __builtin_amdgcn_global_load_lds((gvp)(gB + kbg * N + n0 + 64 + lane),
                                     (lvp)(&b_sm[w * 128 + 64]), 16, 0, 0);
    __syncthreads();
    bf16x8 af[4], bfr[4];
#pragma unroll
    for (int i = 0; i < 4; ++i) af[i]  = aptr[quad * 128 + wm * 64 + i * 16 + l15];
#pragma unroll
    for (int j = 0; j < 4; ++j) bfr[j] = bptr[quad * 128 + wn * 64 + j * 16 + l15];
#pragma unroll
    for (int i = 0; i < 4; ++i)
#pragma unroll
      for (int j = 0; j < 4; ++j)
        acc[i][j] = __builtin_amdgcn_mfma_f32_16x16x32_bf16(af[i], bfr[j], acc[i][j], 0, 0, 0);
    __syncthreads();
  }

  if constexpr (BF16_OUT) {
    // repack through LDS -> bf16x8 (dwordx4) stores, 256B segments
    __shared__ bf16 c_sm[128 * 136];   // +8 pad breaks write-bank aliasing
#pragma unroll
    for (int i = 0; i < 4; ++i) {
      int row = wm * 64 + i * 16 + quad * 4;
#pragma unroll
      for (int j = 0; j < 4; ++j) {
        int col = wn * 64 + j * 16 + l15;
        f32x4 v = acc[i][j];
#pragma unroll
        for (int r = 0; r < 4; ++r)
          c_sm[(row + r) * 136 + col] = (bf16)v[r];
      }
    }
    __syncthreads();
    int rr = tid >> 4, cc = (tid & 15) * 8;
#pragma unroll
    for (int k = 0; k < 8; ++k) {
      int row = k * 16 + rr;
      bf16x8 v = *reinterpret_cast<const bf16x8*>(&c_sm[row * 136 + cc]);
      *reinterpret_cast<bf16x8*>(&outB[(size_t)(m0 + row) * N + n0 + cc]) = v;
    }
  } else {
#pragma unroll
    for (int i = 0; i < 4; ++i) {
      int row = m0 + wm * 64 + i * 16 + quad * 4;
#pragma unroll
      for (int j = 0; j < 4; ++j) {
        int col = n0 + wn * 64 + j * 16 + l15;
        f32x4 v = acc[i][j];
        float bv = bias[col] + bias2[col];
#pragma unroll
        for (int r = 0; r < 4; ++r)
          outF[(size_t)(row + r) * N + col] = v[r] + bv;
      }
    }
  }
}

// ---------- per-step scan kernel (fallback path only) ----------
__global__ __launch_bounds__(256) void scan_step3(
    const bf16* __restrict__ A, int trel, int Tc,
    const bf16* __restrict__ Ubf, const float* __restrict__ wx,
    const float* __restrict__ Vb,
    const bf16* __restrict__ hprev, bf16* __restrict__ hnext,
    float* __restrict__ cst, float* __restrict__ out, int t) {
  __shared__ bf16 U_s[4 * Hk];
  __shared__ float gate_s[64];
  __shared__ float m_s[16];
  int tid = threadIdx.x;
  int j = blockIdx.x;
  int b = tid >> 4, sm = tid & 15;

  const bf16* Ar = A + ((size_t)b * Tc + trel) * NVk + (size_t)j * Hk;
  uint4 av[4];
#pragma unroll
  for (int i = 0; i < 4; ++i)
    av[i] = *reinterpret_cast<const uint4*>(Ar + i * 128 + sm * 8);

  uint4 hv[4];
#pragma unroll
  for (int i = 0; i < 4; ++i)
    hv[i] = *reinterpret_cast<const uint4*>(hprev + b * Hk + i * 128 + sm * 8);

  {
    int r = tid >> 6, e = (tid & 63) * 8;
    *reinterpret_cast<uint4*>(U_s + r * Hk + e) =
        *reinterpret_cast<const uint4*>(Ubf + ((size_t)r * Hk + j) * Hk + e);
  }
  __syncthreads();

  float hf[4][8];
#pragma unroll
  for (int i = 0; i < 4; ++i) {
    unsigned ux = hv[i].x, uy = hv[i].y, uz = hv[i].z, uw = hv[i].w;
    hf[i][0] = bflo(ux); hf[i][1] = bfhi(ux);
    hf[i][2] = bflo(uy); hf[i][3] = bfhi(uy);
    hf[i][4] = bflo(uz); hf[i][5] = bfhi(uz);
    hf[i][6] = bflo(uw); hf[i][7] = bfhi(uw);
  }

  float accs[5] = {0.f, 0.f, 0.f, 0.f, 0.f};
  const uint4* Uq = reinterpret_cast<const uint4*>(U_s);
#pragma unroll
  for (int i = 0; i < 4; ++i) {
#pragma unroll
    for (int q = 0; q < 4; ++q) {
      uint4 u = Uq[q * 64 + i * 16 + sm];
      accs[q] += bflo(u.x) * hf[i][0] + bfhi(u.x) * hf[i][1]
               + bflo(u.y) * hf[i][2] + bfhi(u.y) * hf[i][3]
               + bflo(u.z) * hf[i][4] + bfhi(u.z) * hf[i][5]
               + bflo(u.w) * hf[i][6] + bfhi(u.w) * hf[i][7];
    }
    uint4 a = av[i];
    accs[4] += bflo(a.x) * hf[i][0] + bfhi(a.x) * hf[i][1]
             + bflo(a.y) * hf[i][2] + bfhi(a.y) * hf[i][3]
             + bflo(a.z) * hf[i][4] + bfhi(a.z) * hf[i][5]
             + bflo(a.w) * hf[i][6] + bfhi(a.w) * hf[i][7];
  }
#pragma unroll
  for (int d = 1; d < 16; d <<= 1) {
#pragma unroll
    for (int k = 0; k < 5; ++k) accs[k] += __shfl_xor(accs[k], d);
  }
  if (sm == 0) {
    const float* wxr = wx + ((size_t)b * Tk + t) * Gk + j;
#pragma unroll
    for (int q = 0; q < 4; ++q) gate_s[q * 16 + b] = accs[q] + wxr[q * Hk];
    m_s[b] = accs[4];
  }
  __syncthreads();

  if (tid < 16) {
    int bb = tid;
    float gi = gate_s[bb], gf = gate_s[16 + bb];
    float go = gate_s[32 + bb], gg = gate_s[48 + bb];
    float iv = 1.f / (1.f + __expf(-gi));
    float fv = 1.f / (1.f + __expf(-gf));
    float ov = 1.f / (1.f + __expf(-go));
    float gv = tanhf(gg);
    float mv = tanhf(m_s[bb] + Vb[j]);
    int idx = bb * Hk + j;
    float c = fv * cst[idx] + iv * gv + 0.1f * mv;
    cst[idx] = c;
    float h = ov * tanhf(c);
    hnext[idx] = (bf16)h;
    out[((size_t)bb * Tk + t) * Hk + j] = h;
    if (t == Tk - 1) {
      out[(size_t)Bk * Tk * Hk + idx] = h;
      out[(size_t)Bk * Tk * Hk + Bk * Hk + idx] = c;
    }
  }
}

// ---------- monotonic slot barrier for 256 blocks ----------
// slot[bid] (bar[0..255]) and gen (bar[1024]) only ever increase: no resets,
// no RMWs, no ABA -> cannot deadlock from reset races. All traffic is relaxed
// agent-scope (sc1): zero cache-maintenance instructions.
__device__ __forceinline__ void gbar_slots(int* bar, int target) {
  __syncthreads();   // compiler drains each wave's vmcnt before s_barrier
  int tid = threadIdx.x;
  if (blockIdx.x == 0) {
    if (tid < 64) {                        // wave 0 = sweeper
      if (tid == 0) { VMWAIT; st_rlx(bar + 0, target); }
      for (;;) {
        bool ok = ld_rlx(bar + tid)       >= target &&
                  ld_rlx(bar + 64 + tid)  >= target &&
                  ld_rlx(bar + 128 + tid) >= target &&
                  ld_rlx(bar + 192 + tid) >= target;
        if (__all(ok)) break;
        __builtin_amdgcn_s_sleep(2);
      }
      if (tid == 0) st_rlx(bar + 1024, target);
    }
  } else if (tid == 0) {
    VMWAIT;                                // own wave's h-stores ack'd at fabric
    st_rlx(bar + blockIdx.x, target);
    while (ld_rlx(bar + 1024) < target) __builtin_amdgcn_s_sleep(2);
  }
  __syncthreads();
}

// ---------- persistent cooperative scan, fence-free h exchange ----------
// 256 blocks x 256 threads, block owns j0=2*bid and j0+1. U (8 rows) staged to
// LDS once per chunk, c in regs, A[t+1] prefetched to regs pre-barrier.
// h moves via relaxed agent-scope (sc1) atomics -> coherent point, no fences.
__global__ __launch_bounds__(256) void scan_persist2(
    const bf16* __restrict__ A, int Tc, int c0,
    const bf16* __restrict__ Ubf, const float* __restrict__ wx,
    const float* __restrict__ Vb, bf16* __restrict__ hbuf,
    float* __restrict__ cst, float* __restrict__ out, int* __restrict__ bar) {
  __shared__ bf16 U_s[8 * 512];     // 8 KB
  __shared__ float gate_s[128];     // [jj][q][b]
  __shared__ float m_s[32];         // [jj][b]
  int tid = threadIdx.x;
  int j0 = blockIdx.x * 2;
  int b = tid >> 4, sm = tid & 15;

  // stage U rows r=q*2+jj  <-  g = q*512 + j0 + jj
  {
    int r = tid >> 5;               // 0..7
    int q = r >> 1, jj = r & 1;
    int e = (tid & 31) * 8;
#pragma unroll
    for (int k = 0; k < 2; ++k)
      *reinterpret_cast<uint4*>(U_s + r * 512 + e + k * 256) =
          *reinterpret_cast<const uint4*>(
              Ubf + ((size_t)(q * 512 + j0 + jj)) * 512 + e + k * 256);
  }
  float c_reg = 0.f, vb = 0.f;
  if (tid < 32) {
    int bb = tid & 15, jj = tid >> 4;
    c_reg = cst[bb * Hk + j0 + jj];
    vb = Vb[j0 + jj];
  }
  __syncthreads();

  const uint4* Aq = reinterpret_cast<const uint4*>(A);
  const uint4* Uq = reinterpret_cast<const uint4*>(U_s);
  size_t abase = (size_t)(b * Tc) * (NVk / 8) + (size_t)j0 * 64 + sm;

  uint4 avA[2][4], avB[2][4];
#pragma unroll
  for (int jj = 0; jj < 2; ++jj)
#pragma unroll
    for (int i = 0; i < 4; ++i) avA[jj][i] = Aq[abase + jj * 64 + i * 16];

  for (int trel = 0; trel < Tc; ++trel) {
    int t = c0 + trel;
    const bf16* hprev = hbuf + (t & 1) * 8192;
    bf16* hnext = hbuf + ((t + 1) & 1) * 8192;

    // h read: relaxed agent atomics (sc1, fresh cross-XCD, no fences)
    unsigned long long hw[4][2];
    const unsigned long long* Hd =
        reinterpret_cast<const unsigned long long*>(hprev);
#pragma unroll
    for (int i = 0; i < 4; ++i)
#pragma unroll
      for (int k = 0; k < 2; ++k)
        hw[i][k] = __hip_atomic_load(Hd + b * 128 + i * 32 + sm * 2 + k,
                                     __ATOMIC_RELAXED, __HIP_MEMORY_SCOPE_AGENT);

    // wx gate loads issued early; latency hides under the MAC loop
    float wxq[2][4] = {{0.f, 0.f, 0.f, 0.f}, {0.f, 0.f, 0.f, 0.f}};
    if (sm == 0) {
      const float* wxr = wx + ((size_t)b * Tk + t) * Gk + j0;
#pragma unroll
      for (int jj = 0; jj < 2; ++jj)
#pragma unroll
        for (int q = 0; q < 4; ++q) wxq[jj][q] = wxr[q * Hk + jj];
    }

    float accs[2][5] = {{0.f, 0.f, 0.f, 0.f, 0.f}, {0.f, 0.f, 0.f, 0.f, 0.f}};
#pragma unroll
    for (int i = 0; i < 4; ++i) {
      float hf[8];
      unsigned lo0 = (unsigned)hw[i][0], hi0 = (unsigned)(hw[i][0] >> 32);
      unsigned lo1 = (unsigned)hw[i][1], hi1 = (unsigned)(hw[i][1] >> 32);
      hf[0] = bflo(lo0); hf[1] = bfhi(lo0);
      hf[2] = bflo(hi0); hf[3] = bfhi(hi0);
      hf[4] = bflo(lo1); hf[5] = bfhi(lo1);
      hf[6] = bflo(hi1); hf[7] = bfhi(hi1);
#pragma unroll
      for (int jj = 0; jj < 2; ++jj) {
#pragma unroll
        for (int q = 0; q < 4; ++q) {
          uint4 u = Uq[(q * 2 + jj) * 64 + i * 16 + sm];
          accs[jj][q] += bflo(u.x) * hf[0] + bfhi(u.x) * hf[1]
                       + bflo(u.y) * hf[2] + bfhi(u.y) * hf[3]
                       + bflo(u.z) * hf[4] + bfhi(u.z) * hf[5]
                       + bflo(u.w) * hf[6] + bfhi(u.w) * hf[7];
        }
        uint4 a = avA[jj][i];
        accs[jj][4] += bflo(a.x) * hf[0] + bfhi(a.x) * hf[1]
                     + bflo(a.y) * hf[2] + bfhi(a.y) * hf[3]
                     + bflo(a.z) * hf[4] + bfhi(a.z) * hf[5]
                     + bflo(a.w) * hf[6] + bfhi(a.w) * hf[7];
      }
    }

    // prefetch A[t+1] (plain cached loads): drains during barrier
    if (trel + 1 < Tc) {
      size_t nb = abase + (size_t)(trel + 1) * (NVk / 8);
#pragma unroll
      for (int jj = 0; jj < 2; ++jj)
#pragma unroll
        for (int i = 0; i < 4; ++i) avB[jj][i] = Aq[nb + jj * 64 + i * 16];
    }

#pragma unroll
    for (int d = 1; d < 16; d <<= 1) {
#pragma unroll
      for (int jj = 0; jj < 2; ++jj)
#pragma unroll
        for (int k = 0; k < 5; ++k) accs[jj][k] += __shfl_xor(accs[jj][k], d);
    }
    if (sm == 0) {
#pragma unroll
      for (int jj = 0; jj < 2; ++jj) {
#pragma unroll
        for (int q = 0; q < 4; ++q)
          gate_s[jj * 64 + q * 16 + b] = accs[jj][q] + wxq[jj][q];
        m_s[jj * 16 + b] = accs[jj][4];
      }
    }
    __syncthreads();

    if (tid < 32) {
      int bb = tid & 15, jj = tid >> 4;
      float gi = gate_s[jj * 64 + bb];
      float gf = gate_s[jj * 64 + 16 + bb];
      float go = gate_s[jj * 64 + 32 + bb];
      float gg = gate_s[jj * 64 + 48 + bb];
      float iv = 1.f / (1.f + __expf(-gi));
      float fv = 1.f / (1.f + __expf(-gf));
      float ov = 1.f / (1.f + __expf(-go));
      float gv = tanhf(gg);
      float mv = tanhf(m_s[jj * 16 + bb] + vb);
      float c = fv * c_reg + iv * gv + 0.1f * mv;
      c_reg = c;
      float h = ov * tanhf(c);
      // pack (j0, j0+1) into one dword; lanes 0-15 store via relaxed atomic
      float hOther = __shfl_down(h, 16);
      if (jj == 0) {
        unsigned lo = (unsigned)__builtin_bit_cast(unsigned short, (bf16)h);
        unsigned hi = (unsigned)__builtin_bit_cast(unsigned short, (bf16)hOther);
        unsigned u = lo | (hi << 16);
        unsigned* hp = reinterpret_cast<unsigned*>(hnext) + ((bb * Hk + j0) >> 1);
        __hip_atomic_store(hp, u, __ATOMIC_RELAXED, __HIP_MEMORY_SCOPE_AGENT);
      }
      out[((size_t)bb * Tk + t) * Hk + j0 + jj] = h;
      if (t == Tk - 1) {
        out[(size_t)Bk * Tk * Hk + bb * Hk + j0 + jj] = h;                 // hT
        out[(size_t)Bk * Tk * Hk + Bk * Hk + bb * Hk + j0 + jj] = c;       // cT
      }
    }

    if (trel + 1 < Tc) {
      gbar_slots(bar, t + 1);
#pragma unroll
      for (int jj = 0; jj < 2; ++jj)
#pragma unroll
        for (int i = 0; i < 4; ++i) avA[jj][i] = avB[jj][i];
    }
  }
  if (tid < 32) cst[(tid & 15) * Hk + j0 + (tid >> 4)] = c_reg;
}

// ---------- host ----------
extern "C" void kernel_launch(void* const* d_in, const int* in_sizes, int n_in,
                              void* d_out, int out_size, void* d_ws, size_t ws_size,
                              hipStream_t stream) {
  const float* x  = (const float*)d_in[0];
  const float* Ww = (const float*)d_in[1];
  const float* Wb = (const float*)d_in[2];
  const float* Uw = (const float*)d_in[3];
  const float* Ub = (const float*)d_in[4];
  const float* Vw = (const float*)d_in[5];
  const float* Vb = (const float*)d_in[6];
  float* out = (float*)d_out;

  char* ws = (char*)d_ws;
  size_t off = 0;
  auto alloc = [&](size_t bytes) -> void* {
    void* p = ws + off;
    off = (off + bytes + 255) & ~(size_t)255;
    return p;
  };
  bf16*  xp   = (bf16*)alloc((size_t)Bk * Tk * Dk * 2);   //   4 MB packed x
  bf16*  V2p  = (bf16*)alloc((size_t)32 * NVk * 8 * 2);   // 134 MB
  bf16*  Wp   = (bf16*)alloc((size_t)32 * Gk * 8 * 2);    //   1 MB
  bf16*  Ubf  = (bf16*)alloc((size_t)Gk * Hk * 2);        //   2 MB
  float* wx   = (float*)alloc((size_t)Bk * Tk * Gk * 4);  //  67 MB
  bf16*  hbuf = (bf16*)alloc((size_t)16384 * 2);          // double buffer, bf16
  float* cws  = (float*)alloc((size_t)8192 * 4);
  int*   bar  = (int*)alloc(2048 * sizeof(int));          // slot barrier state
  size_t fixedBytes = off;

  int Tc = 512;   // time-chunk for A; shrink until it fits the workspace
  while (Tc > 8 && fixedBytes + (size_t)Bk * Tc * Hk * Hk * 2 > ws_size) Tc >>= 1;
  bf16* A_ws = (bf16*)alloc((size_t)Bk * Tc * Hk * Hk * 2);
  int tcShift = 31 - __builtin_clz((unsigned)Tc);
  int mt = Bk * Tc / 128;                 // m-tiles per B-panel
  int mtShift = 31 - __builtin_clz((unsigned)mt);

  pack_x<<<32, 256, 0, stream>>>(x, xp);
  cvt_f32_bf16<<<512, 256, 0, stream>>>(Uw, Ubf, 131072);
  pack_V<<<1024, 256, 0, stream>>>(Vw, V2p);
  pack_W<<<8, 256, 0, stream>>>(Ww, Wp);
  init_state<<<64, 256, 0, stream>>>(hbuf, cws, bar);

  // wx = x @ W^T + (W_b + U_b)   (M=8192, N=2048, K=256), identity row map
  gemm128<false><<<dim3(64, 16), 256, 0, stream>>>(xp, Wp, wx, nullptr, Wb, Ub,
                                                   Gk, 8192, 0, 511, 9, -1);

  for (int c0 = 0; c0 < Tk; c0 += Tc) {
    // A[b, t0..t0+Tc, j, h'] = x(b,t) . V(:,d,:)   (M=16*Tc, N=262144, K=256)
    gemm128<true><<<dim3(mt * (NVk / 128)), 256, 0, stream>>>(
        xp, V2p, nullptr, A_ws, nullptr, nullptr, NVk, 8192, c0, Tc - 1,
        tcShift, mtShift);

    int TcV = Tc, c0V = c0;
    void* args[] = {(void*)&A_ws, (void*)&TcV, (void*)&c0V, (void*)&Ubf,
                    (void*)&wx, (void*)&Vb, (void*)&hbuf, (void*)&cws,
                    (void*)&out, (void*)&bar};
    hipError_t e = hipLaunchCooperativeKernel((const void*)scan_persist2,
                                              dim3(NBLK), dim3(256), args, 0, stream);
    if (e != hipSuccess) {
      // fallback: per-step launches (previous verified path)
      for (int t = c0; t < c0 + Tc; ++t)
        scan_step3<<<512, 256, 0, stream>>>(
            A_ws, t - c0, Tc, Ubf, wx, Vb,
            hbuf + (t & 1) * 8192, hbuf + ((t + 1) & 1) * 8192,
            cws, out, t);
    }
  }
}

// Round 4
// 6262.653 us; speedup vs baseline: 2.3139x; 1.0011x over previous
//
#include <hip/hip_runtime.h>
#include <cstdint>
#include <cstddef>

#define Dk 256
#define Hk 512
#define Bk 16
#define Tk 512
#define Gk 2048      // 4H
#define NVk 262144   // H*H
#define NBLK 256     // persistent scan blocks (2 j's each)

typedef __bf16 bf16;
typedef __bf16 bf16x8 __attribute__((ext_vector_type(8)));
typedef float  f32x4  __attribute__((ext_vector_type(4)));
typedef const __attribute__((address_space(1))) void* gvp;
typedef __attribute__((address_space(3))) void* lvp;

__device__ __forceinline__ float bflo(unsigned u) {
  u <<= 16; return __builtin_bit_cast(float, u);
}
__device__ __forceinline__ float bfhi(unsigned u) {
  u &= 0xffff0000u; return __builtin_bit_cast(float, u);
}

// relaxed agent-scope atomics -> sc1 accesses at the coherent point; no
// buffer_wbl2 / buffer_inv cache maintenance is ever emitted.
__device__ __forceinline__ int ld_rlx(const int* p) {
  return __hip_atomic_load(p, __ATOMIC_RELAXED, __HIP_MEMORY_SCOPE_AGENT);
}
__device__ __forceinline__ void st_rlx(int* p, int v) {
  __hip_atomic_store(p, v, __ATOMIC_RELAXED, __HIP_MEMORY_SCOPE_AGENT);
}
#define VMWAIT asm volatile("s_waitcnt vmcnt(0)" ::: "memory")

// ---------- prep kernels ----------
__global__ __launch_bounds__(256) void cvt_f32_bf16(const float* __restrict__ in,
                                                    bf16* __restrict__ out, int n8) {
  int i = blockIdx.x * 256 + threadIdx.x;
  if (i >= n8) return;
  const float4* p = reinterpret_cast<const float4*>(in) + (size_t)i * 2;
  float4 a = p[0], b = p[1];
  bf16x8 v;
  v[0] = (bf16)a.x; v[1] = (bf16)a.y; v[2] = (bf16)a.z; v[3] = (bf16)a.w;
  v[4] = (bf16)b.x; v[5] = (bf16)b.y; v[6] = (bf16)b.z; v[7] = (bf16)b.w;
  *reinterpret_cast<bf16x8*>(out + (size_t)i * 8) = v;
}

// V_w[j][d*512+h'] (fp32) -> packed B: V2p[(d/8)][n=(j,h')][d%8] (bf16)
__global__ __launch_bounds__(256) void pack_V(const float* __restrict__ Vw,
                                              bf16* __restrict__ V2p) {
  int n = blockIdx.x * 256 + threadIdx.x;        // 0..262143
  int j = n >> 9, hp = n & 511;
  const float* src = Vw + (size_t)j * 131072 + hp;
  for (int kb = 0; kb < 32; ++kb) {
    bf16x8 v;
#pragma unroll
    for (int r = 0; r < 8; ++r) v[r] = (bf16)src[(size_t)(kb * 8 + r) * 512];
    *reinterpret_cast<bf16x8*>(V2p + ((size_t)kb * NVk + n) * 8) = v;
  }
}

// W_w[g][d] (fp32) -> packed B: Wp[(d/8)][g][d%8] (bf16)
__global__ __launch_bounds__(256) void pack_W(const float* __restrict__ Ww,
                                              bf16* __restrict__ Wp) {
  int g = blockIdx.x * 256 + threadIdx.x;        // 0..2047
  const float* src = Ww + (size_t)g * 256;
  for (int kb = 0; kb < 32; ++kb) {
    bf16x8 v;
#pragma unroll
    for (int r = 0; r < 8; ++r) v[r] = (bf16)src[kb * 8 + r];
    *reinterpret_cast<bf16x8*>(Wp + ((size_t)kb * Gk + g) * 8) = v;
  }
}

// x[row][d] (fp32, row=b*512+t) -> packed A: xp[(d/8)][row][d%8] (bf16)
__global__ __launch_bounds__(256) void pack_x(const float* __restrict__ x,
                                              bf16* __restrict__ xp) {
  int row = blockIdx.x * 256 + threadIdx.x;      // 0..8191
  const float* src = x + (size_t)row * 256;
  for (int kb = 0; kb < 32; ++kb) {
    bf16x8 v;
#pragma unroll
    for (int r = 0; r < 8; ++r) v[r] = (bf16)src[kb * 8 + r];
    *reinterpret_cast<bf16x8*>(xp + ((size_t)kb * 8192 + row) * 8) = v;
  }
}

__global__ __launch_bounds__(256) void init_state(bf16* __restrict__ hbuf,
                                                  float* __restrict__ cws,
                                                  int* __restrict__ bar) {
  int i = blockIdx.x * 256 + threadIdx.x;
  if (i < 16384) hbuf[i] = (bf16)0.f;
  if (i < 8192)  cws[i]  = 0.f;
  if (i < 2048)  bar[i]  = 0;
}

// ---------- 128x128 tile MFMA GEMM with global_load_lds staging ----------
// swzShift >= 0: 1D grid of (mt*2048) blocks, mt = 1<<swzShift m-tiles.
// Same-B-panel blocks get ids congruent mod 8 -> same XCD (round-robin heur).
// BF16_OUT: output in TILE-LOCAL layout A[nblk][m (chunk-local)][128].
template <bool BF16_OUT>
__global__ __launch_bounds__(256) void gemm128(const bf16* __restrict__ Ap,
                                               const bf16* __restrict__ Bp,
                                               float* __restrict__ outF,
                                               bf16* __restrict__ outB,
                                               const float* __restrict__ bias,
                                               const float* __restrict__ bias2,
                                               int N, int Mtot,
                                               int t0, int tcMask, int tcShift,
                                               int swzShift) {
  __shared__ uint4 a_sm[512];   // [kb(4)][m(128)] 16B each
  __shared__ uint4 b_sm[512];   // [kb(4)][n(128)]
  int tid = threadIdx.x;
  int lane = tid & 63, w = tid >> 6;
  int quad = lane >> 4, l15 = lane & 15;
  int wm = w >> 1, wn = w & 1;
  int m0, n0;
  if (swzShift >= 0) {
    int id = blockIdx.x;
    int r = id & 7, q = id >> 3;
    m0 = (q & ((1 << swzShift) - 1)) << 7;
    n0 = (r + ((q >> swzShift) << 3)) << 7;
  } else {
    m0 = blockIdx.x << 7; n0 = blockIdx.y << 7;
  }

  f32x4 acc[4][4];
#pragma unroll
  for (int i = 0; i < 4; ++i)
#pragma unroll
    for (int j = 0; j < 4; ++j) acc[i][j] = (f32x4){0.f, 0.f, 0.f, 0.f};

  int gm0 = m0 + lane, gm1 = m0 + 64 + lane;
  int xr0 = ((gm0 >> tcShift) << 9) + t0 + (gm0 & tcMask);
  int xr1 = ((gm1 >> tcShift) << 9) + t0 + (gm1 & tcMask);
  const uint4* gA = reinterpret_cast<const uint4*>(Ap);
  const uint4* gB = reinterpret_cast<const uint4*>(Bp);

  const bf16x8* aptr = reinterpret_cast<const bf16x8*>(a_sm);
  const bf16x8* bptr = reinterpret_cast<const bf16x8*>(b_sm);

  for (int kk = 0; kk < 8; ++kk) {
    size_t kbg = (size_t)(kk * 4 + w);
    __builtin_amdgcn_global_load_lds((gvp)(gA + kbg * Mtot + xr0),
                                     (lvp)(&a_sm[w * 128]), 16, 0, 0);
    __builtin_amdgcn_global_load_lds((gvp)(gA + kbg * Mtot + xr1),
                                     (lvp)(&a_sm[w * 128 + 64]), 16, 0, 0);
    __builtin_amdgcn_global_load_lds((gvp)(gB + kbg * N + n0 + lane),
                                     (lvp)(&b_sm[w * 128]), 16, 0, 0);
    __builtin_amdgcn_global_load_lds((gvp)(gB + kbg * N + n0 + 64 + lane),
                                     (lvp)(&b_sm[w * 128 + 64]), 16, 0, 0);
    __syncthreads();
    bf16x8 af[4], bfr[4];
#pragma unroll
    for (int i = 0; i < 4; ++i) af[i]  = aptr[quad * 128 + wm * 64 + i * 16 + l15];
#pragma unroll
    for (int j = 0; j < 4; ++j) bfr[j] = bptr[quad * 128 + wn * 64 + j * 16 + l15];
#pragma unroll
    for (int i = 0; i < 4; ++i)
#pragma unroll
      for (int j = 0; j < 4; ++j)
        acc[i][j] = __builtin_amdgcn_mfma_f32_16x16x32_bf16(af[i], bfr[j], acc[i][j], 0, 0, 0);
    __syncthreads();
  }

  if constexpr (BF16_OUT) {
    // Repack via swizzled 64x136 LDS (2 passes) -> contiguous 256B dwordx4
    // stores into tile-local layout out[nblk][m][128].
    __shared__ bf16 c_sm[64 * 136];
    int Mc = 128 << swzShift;                       // chunk-local M
    size_t tbase = ((size_t)(n0 >> 7) * Mc + m0) * 128;
#pragma unroll
    for (int p = 0; p < 2; ++p) {
      if (wm == p) {
#pragma unroll
        for (int i = 0; i < 4; ++i) {
          int rl = i * 16 + quad * 4;              // local row base
          int cshift = quad * 16;                  // == ((rl>>2)&3)*16
#pragma unroll
          for (int j = 0; j < 4; ++j) {
            int col = wn * 64 + j * 16 + l15;
            int cs = (col + cshift) & 127;
            f32x4 v = acc[i][j];
#pragma unroll
            for (int r = 0; r < 4; ++r)
              c_sm[(rl + r) * 136 + cs] = (bf16)v[r];
          }
        }
      }
      __syncthreads();
      int rr = tid >> 4, cc = (tid & 15) * 8;
      int rshift = ((rr >> 2) & 3) * 16;
      int csr = (cc + rshift) & 127;
#pragma unroll
      for (int k = 0; k < 4; ++k) {
        int rl = k * 16 + rr;
        bf16x8 v = *reinterpret_cast<const bf16x8*>(&c_sm[rl * 136 + csr]);
        *reinterpret_cast<bf16x8*>(&outB[tbase + (size_t)(p * 64 + rl) * 128 + cc]) = v;
      }
      __syncthreads();
    }
  } else {
#pragma unroll
    for (int i = 0; i < 4; ++i) {
      int row = m0 + wm * 64 + i * 16 + quad * 4;
#pragma unroll
      for (int j = 0; j < 4; ++j) {
        int col = n0 + wn * 64 + j * 16 + l15;
        f32x4 v = acc[i][j];
        float bv = bias[col] + bias2[col];
#pragma unroll
        for (int r = 0; r < 4; ++r)
          outF[(size_t)(row + r) * N + col] = v[r] + bv;
      }
    }
  }
}

// ---------- per-step scan kernel (fallback path only) ----------
// A in tile-local layout: A[nblk][m=b*Tc+trel][128]
__global__ __launch_bounds__(256) void scan_step3(
    const bf16* __restrict__ A, int trel, int Tc,
    const bf16* __restrict__ Ubf, const float* __restrict__ wx,
    const float* __restrict__ Vb,
    const bf16* __restrict__ hprev, bf16* __restrict__ hnext,
    float* __restrict__ cst, float* __restrict__ out, int t) {
  __shared__ bf16 U_s[4 * Hk];
  __shared__ float gate_s[64];
  __shared__ float m_s[16];
  int tid = threadIdx.x;
  int j = blockIdx.x;
  int b = tid >> 4, sm = tid & 15;
  size_t Mc = (size_t)Bk * Tc;

  const uint4* Aq = reinterpret_cast<const uint4*>(A);
  uint4 av[4];
#pragma unroll
  for (int i = 0; i < 4; ++i)
    av[i] = Aq[((size_t)(j * 4 + i) * Mc + (size_t)b * Tc + trel) * 16 + sm];

  uint4 hv[4];
#pragma unroll
  for (int i = 0; i < 4; ++i)
    hv[i] = *reinterpret_cast<const uint4*>(hprev + b * Hk + i * 128 + sm * 8);

  {
    int r = tid >> 6, e = (tid & 63) * 8;
    *reinterpret_cast<uint4*>(U_s + r * Hk + e) =
        *reinterpret_cast<const uint4*>(Ubf + ((size_t)r * Hk + j) * Hk + e);
  }
  __syncthreads();

  float hf[4][8];
#pragma unroll
  for (int i = 0; i < 4; ++i) {
    unsigned ux = hv[i].x, uy = hv[i].y, uz = hv[i].z, uw = hv[i].w;
    hf[i][0] = bflo(ux); hf[i][1] = bfhi(ux);
    hf[i][2] = bflo(uy); hf[i][3] = bfhi(uy);
    hf[i][4] = bflo(uz); hf[i][5] = bfhi(uz);
    hf[i][6] = bflo(uw); hf[i][7] = bfhi(uw);
  }

  float accs[5] = {0.f, 0.f, 0.f, 0.f, 0.f};
  const uint4* Uq = reinterpret_cast<const uint4*>(U_s);
#pragma unroll
  for (int i = 0; i < 4; ++i) {
#pragma unroll
    for (int q = 0; q < 4; ++q) {
      uint4 u = Uq[q * 64 + i * 16 + sm];
      accs[q] += bflo(u.x) * hf[i][0] + bfhi(u.x) * hf[i][1]
               + bflo(u.y) * hf[i][2] + bfhi(u.y) * hf[i][3]
               + bflo(u.z) * hf[i][4] + bfhi(u.z) * hf[i][5]
               + bflo(u.w) * hf[i][6] + bfhi(u.w) * hf[i][7];
    }
    uint4 a = av[i];
    accs[4] += bflo(a.x) * hf[i][0] + bfhi(a.x) * hf[i][1]
             + bflo(a.y) * hf[i][2] + bfhi(a.y) * hf[i][3]
             + bflo(a.z) * hf[i][4] + bfhi(a.z) * hf[i][5]
             + bflo(a.w) * hf[i][6] + bfhi(a.w) * hf[i][7];
  }
#pragma unroll
  for (int d = 1; d < 16; d <<= 1) {
#pragma unroll
    for (int k = 0; k < 5; ++k) accs[k] += __shfl_xor(accs[k], d);
  }
  if (sm == 0) {
    const float* wxr = wx + ((size_t)b * Tk + t) * Gk + j;
#pragma unroll
    for (int q = 0; q < 4; ++q) gate_s[q * 16 + b] = accs[q] + wxr[q * Hk];
    m_s[b] = accs[4];
  }
  __syncthreads();

  if (tid < 16) {
    int bb = tid;
    float gi = gate_s[bb], gf = gate_s[16 + bb];
    float go = gate_s[32 + bb], gg = gate_s[48 + bb];
    float iv = 1.f / (1.f + __expf(-gi));
    float fv = 1.f / (1.f + __expf(-gf));
    float ov = 1.f / (1.f + __expf(-go));
    float gv = tanhf(gg);
    float mv = tanhf(m_s[bb] + Vb[j]);
    int idx = bb * Hk + j;
    float c = fv * cst[idx] + iv * gv + 0.1f * mv;
    cst[idx] = c;
    float h = ov * tanhf(c);
    hnext[idx] = (bf16)h;
    out[((size_t)bb * Tk + t) * Hk + j] = h;
    if (t == Tk - 1) {
      out[(size_t)Bk * Tk * Hk + idx] = h;
      out[(size_t)Bk * Tk * Hk + Bk * Hk + idx] = c;
    }
  }
}

// ---------- monotonic 16x16 tree barrier, contention-free ----------
// bar[bid]           : arrival slots (monotonic step counters)
// bar[256 + g*32]    : ggen[g]  (group-complete, own 128B line)
// bar[768 + g*32]    : gbc[g]   (broadcast, own 128B line)
// Max 16 pollers per line; all traffic relaxed agent-scope (sc1); values
// only increase -> no resets, no ABA, deadlock-free.
__device__ __forceinline__ void gbar_tree(int* bar, int target) {
  __syncthreads();                    // drains vmcnt (h stores ack'd) pre-arrival
  int tid = threadIdx.x;
  int bid = blockIdx.x, g = bid >> 4;
  if (tid == 0) { VMWAIT; st_rlx(bar + bid, target); }
  if ((bid & 15) == 0) {
    if (tid < 16) {
      // sweep my group's 16 slots (one coalesced 64B line)
      while (!__all(ld_rlx(bar + g * 16 + tid) >= target))
        __builtin_amdgcn_s_sleep(1);
      if (tid == 0) st_rlx(bar + 256 + g * 32, target);
      // sweep all 16 ggen lines (16 pollers per line max)
      while (!__all(ld_rlx(bar + 256 + tid * 32) >= target))
        __builtin_amdgcn_s_sleep(1);
      if (tid == 0) st_rlx(bar + 768 + g * 32, target);
    }
  } else {
    if (tid == 0) {
      while (ld_rlx(bar + 768 + g * 32) < target)
        __builtin_amdgcn_s_sleep(1);
    }
  }
  __syncthreads();
}

// ---------- persistent cooperative scan, fence-free h exchange ----------
// 256 blocks x 256 threads, block owns j0=2*bid and j0+1. U (8 rows) staged to
// LDS once per chunk, c in regs, A[t+1] + wx[t+1] prefetched pre-barrier.
// A in tile-local layout A[nblk][m][128].
__global__ __launch_bounds__(256) void scan_persist2(
    const bf16* __restrict__ A, int Tc, int c0,
    const bf16* __restrict__ Ubf, const float* __restrict__ wx,
    const float* __restrict__ Vb, bf16* __restrict__ hbuf,
    float* __restrict__ cst, float* __restrict__ out, int* __restrict__ bar) {
  __shared__ bf16 U_s[8 * 512];     // 8 KB
  __shared__ float gate_s[128];     // [jj][q][b]
  __shared__ float m_s[32];         // [jj][b]
  int tid = threadIdx.x;
  int j0 = blockIdx.x * 2;
  int b = tid >> 4, sm = tid & 15;

  // stage U rows r=q*2+jj  <-  g = q*512 + j0 + jj
  {
    int r = tid >> 5;               // 0..7
    int q = r >> 1, jj = r & 1;
    int e = (tid & 31) * 8;
#pragma unroll
    for (int k = 0; k < 2; ++k)
      *reinterpret_cast<uint4*>(U_s + r * 512 + e + k * 256) =
          *reinterpret_cast<const uint4*>(
              Ubf + ((size_t)(q * 512 + j0 + jj)) * 512 + e + k * 256);
  }
  float c_reg = 0.f, vb = 0.f;
  if (tid < 32) {
    int bb = tid & 15, jj = tid >> 4;
    c_reg = cst[bb * Hk + j0 + jj];
    vb = Vb[j0 + jj];
  }
  __syncthreads();

  const uint4* Aq = reinterpret_cast<const uint4*>(A);
  const uint4* Uq = reinterpret_cast<const uint4*>(U_s);
  size_t Mc16 = (size_t)(Bk * Tc) * 16;   // uint4 per nblk panel
  size_t abase = (size_t)(j0 * 4) * Mc16 + (size_t)(b * Tc) * 16 + sm;

  uint4 avA[2][4], avB[2][4];
#pragma unroll
  for (int jj = 0; jj < 2; ++jj)
#pragma unroll
    for (int i = 0; i < 4; ++i)
      avA[jj][i] = Aq[abase + (size_t)(jj * 4 + i) * Mc16];

  // wx for first step
  float wxqA[2][4] = {{0.f,0.f,0.f,0.f},{0.f,0.f,0.f,0.f}}, wxqB[2][4];
  if (sm == 0) {
    const float* wxr = wx + ((size_t)b * Tk + c0) * Gk + j0;
#pragma unroll
    for (int jj = 0; jj < 2; ++jj)
#pragma unroll
      for (int q = 0; q < 4; ++q) wxqA[jj][q] = wxr[q * Hk + jj];
  }

  for (int trel = 0; trel < Tc; ++trel) {
    int t = c0 + trel;
    const bf16* hprev = hbuf + (t & 1) * 8192;
    bf16* hnext = hbuf + ((t + 1) & 1) * 8192;

    // h read: relaxed agent atomics (sc1, fresh cross-XCD, no fences)
    unsigned long long hw[4][2];
    const unsigned long long* Hd =
        reinterpret_cast<const unsigned long long*>(hprev);
#pragma unroll
    for (int i = 0; i < 4; ++i)
#pragma unroll
      for (int k = 0; k < 2; ++k)
        hw[i][k] = __hip_atomic_load(Hd + b * 128 + i * 32 + sm * 2 + k,
                                     __ATOMIC_RELAXED, __HIP_MEMORY_SCOPE_AGENT);

    float accs[2][5] = {{0.f, 0.f, 0.f, 0.f, 0.f}, {0.f, 0.f, 0.f, 0.f, 0.f}};
#pragma unroll
    for (int i = 0; i < 4; ++i) {
      float hf[8];
      unsigned lo0 = (unsigned)hw[i][0], hi0 = (unsigned)(hw[i][0] >> 32);
      unsigned lo1 = (unsigned)hw[i][1], hi1 = (unsigned)(hw[i][1] >> 32);
      hf[0] = bflo(lo0); hf[1] = bfhi(lo0);
      hf[2] = bflo(hi0); hf[3] = bfhi(hi0);
      hf[4] = bflo(lo1); hf[5] = bfhi(lo1);
      hf[6] = bflo(hi1); hf[7] = bfhi(hi1);
#pragma unroll
      for (int jj = 0; jj < 2; ++jj) {
#pragma unroll
        for (int q = 0; q < 4; ++q) {
          uint4 u = Uq[(q * 2 + jj) * 64 + i * 16 + sm];
          accs[jj][q] += bflo(u.x) * hf[0] + bfhi(u.x) * hf[1]
                       + bflo(u.y) * hf[2] + bfhi(u.y) * hf[3]
                       + bflo(u.z) * hf[4] + bfhi(u.z) * hf[5]
                       + bflo(u.w) * hf[6] + bfhi(u.w) * hf[7];
        }
        uint4 a = avA[jj][i];
        accs[jj][4] += bflo(a.x) * hf[0] + bfhi(a.x) * hf[1]
                     + bflo(a.y) * hf[2] + bfhi(a.y) * hf[3]
                     + bflo(a.z) * hf[4] + bfhi(a.z) * hf[5]
                     + bflo(a.w) * hf[6] + bfhi(a.w) * hf[7];
      }
    }

    // prefetch A[t+1] + wx[t+1]: issued pre-barrier, drain during barrier
    if (trel + 1 < Tc) {
      size_t nb = abase + (size_t)(trel + 1) * 16;
#pragma unroll
      for (int jj = 0; jj < 2; ++jj)
#pragma unroll
        for (int i = 0; i < 4; ++i)
          avB[jj][i] = Aq[nb + (size_t)(jj * 4 + i) * Mc16];
      if (sm == 0) {
        const float* wxr = wx + ((size_t)b * Tk + t + 1) * Gk + j0;
#pragma unroll
        for (int jj = 0; jj < 2; ++jj)
#pragma unroll
          for (int q = 0; q < 4; ++q) wxqB[jj][q] = wxr[q * Hk + jj];
      }
    }

#pragma unroll
    for (int d = 1; d < 16; d <<= 1) {
#pragma unroll
      for (int jj = 0; jj < 2; ++jj)
#pragma unroll
        for (int k = 0; k < 5; ++k) accs[jj][k] += __shfl_xor(accs[jj][k], d);
    }
    if (sm == 0) {
#pragma unroll
      for (int jj = 0; jj < 2; ++jj) {
#pragma unroll
        for (int q = 0; q < 4; ++q)
          gate_s[jj * 64 + q * 16 + b] = accs[jj][q] + wxqA[jj][q];
        m_s[jj * 16 + b] = accs[jj][4];
      }
    }
    __syncthreads();

    if (tid < 32) {
      int bb = tid & 15, jj = tid >> 4;
      float gi = gate_s[jj * 64 + bb];
      float gf = gate_s[jj * 64 + 16 + bb];
      float go = gate_s[jj * 64 + 32 + bb];
      float gg = gate_s[jj * 64 + 48 + bb];
      float iv = 1.f / (1.f + __expf(-gi));
      float fv = 1.f / (1.f + __expf(-gf));
      float ov = 1.f / (1.f + __expf(-go));
      float gv = tanhf(gg);
      float mv = tanhf(m_s[jj * 16 + bb] + vb);
      float c = fv * c_reg + iv * gv + 0.1f * mv;
      c_reg = c;
      float h = ov * tanhf(c);
      // pack (j0, j0+1) into one dword; lanes 0-15 store via relaxed atomic
      float hOther = __shfl_down(h, 16);
      if (jj == 0) {
        unsigned lo = (unsigned)__builtin_bit_cast(unsigned short, (bf16)h);
        unsigned hi = (unsigned)__builtin_bit_cast(unsigned short, (bf16)hOther);
        unsigned u = lo | (hi << 16);
        unsigned* hp = reinterpret_cast<unsigned*>(hnext) + ((bb * Hk + j0) >> 1);
        __hip_atomic_store(hp, u, __ATOMIC_RELAXED, __HIP_MEMORY_SCOPE_AGENT);
      }
      out[((size_t)bb * Tk + t) * Hk + j0 + jj] = h;
      if (t == Tk - 1) {
        out[(size_t)Bk * Tk * Hk + bb * Hk + j0 + jj] = h;                 // hT
        out[(size_t)Bk * Tk * Hk + Bk * Hk + bb * Hk + j0 + jj] = c;       // cT
      }
    }

    if (trel + 1 < Tc) {
      gbar_tree(bar, t + 1);
#pragma unroll
      for (int jj = 0; jj < 2; ++jj) {
#pragma unroll
        for (int i = 0; i < 4; ++i) avA[jj][i] = avB[jj][i];
#pragma unroll
        for (int q = 0; q < 4; ++q) wxqA[jj][q] = wxqB[jj][q];
      }
    }
  }
  if (tid < 32) cst[(tid & 15) * Hk + j0 + (tid >> 4)] = c_reg;
}

// ---------- host ----------
extern "C" void kernel_launch(void* const* d_in, const int* in_sizes, int n_in,
                              void* d_out, int out_size, void* d_ws, size_t ws_size,
                              hipStream_t stream) {
  const float* x  = (const float*)d_in[0];
  const float* Ww = (const float*)d_in[1];
  const float* Wb = (const float*)d_in[2];
  const float* Uw = (const float*)d_in[3];
  const float* Ub = (const float*)d_in[4];
  const float* Vw = (const float*)d_in[5];
  const float* Vb = (const float*)d_in[6];
  float* out = (float*)d_out;

  char* ws = (char*)d_ws;
  size_t off = 0;
  auto alloc = [&](size_t bytes) -> void* {
    void* p = ws + off;
    off = (off + bytes + 255) & ~(size_t)255;
    return p;
  };
  bf16*  xp   = (bf16*)alloc((size_t)Bk * Tk * Dk * 2);   //   4 MB packed x
  bf16*  V2p  = (bf16*)alloc((size_t)32 * NVk * 8 * 2);   // 134 MB
  bf16*  Wp   = (bf16*)alloc((size_t)32 * Gk * 8 * 2);    //   1 MB
  bf16*  Ubf  = (bf16*)alloc((size_t)Gk * Hk * 2);        //   2 MB
  float* wx   = (float*)alloc((size_t)Bk * Tk * Gk * 4);  //  67 MB
  bf16*  hbuf = (bf16*)alloc((size_t)16384 * 2);          // double buffer, bf16
  float* cws  = (float*)alloc((size_t)8192 * 4);
  int*   bar  = (int*)alloc(2048 * sizeof(int));          // barrier state
  size_t fixedBytes = off;

  int Tc = 512;   // time-chunk for A; shrink until it fits the workspace
  while (Tc > 8 && fixedBytes + (size_t)Bk * Tc * Hk * Hk * 2 > ws_size) Tc >>= 1;
  bf16* A_ws = (bf16*)alloc((size_t)Bk * Tc * Hk * Hk * 2);
  int tcShift = 31 - __builtin_clz((unsigned)Tc);
  int mt = Bk * Tc / 128;                 // m-tiles per B-panel
  int mtShift = 31 - __builtin_clz((unsigned)mt);

  pack_x<<<32, 256, 0, stream>>>(x, xp);
  cvt_f32_bf16<<<512, 256, 0, stream>>>(Uw, Ubf, 131072);
  pack_V<<<1024, 256, 0, stream>>>(Vw, V2p);
  pack_W<<<8, 256, 0, stream>>>(Ww, Wp);
  init_state<<<64, 256, 0, stream>>>(hbuf, cws, bar);

  // wx = x @ W^T + (W_b + U_b)   (M=8192, N=2048, K=256), identity row map
  gemm128<false><<<dim3(64, 16), 256, 0, stream>>>(xp, Wp, wx, nullptr, Wb, Ub,
                                                   Gk, 8192, 0, 511, 9, -1);

  for (int c0 = 0; c0 < Tk; c0 += Tc) {
    // A[b, t0..t0+Tc, j, h'] = x(b,t) . V(:,d,:)   (M=16*Tc, N=262144, K=256)
    gemm128<true><<<dim3(mt * (NVk / 128)), 256, 0, stream>>>(
        xp, V2p, nullptr, A_ws, nullptr, nullptr, NVk, 8192, c0, Tc - 1,
        tcShift, mtShift);

    int TcV = Tc, c0V = c0;
    void* args[] = {(void*)&A_ws, (void*)&TcV, (void*)&c0V, (void*)&Ubf,
                    (void*)&wx, (void*)&Vb, (void*)&hbuf, (void*)&cws,
                    (void*)&out, (void*)&bar};
    hipError_t e = hipLaunchCooperativeKernel((const void*)scan_persist2,
                                              dim3(NBLK), dim3(256), args, 0, stream);
    if (e != hipSuccess) {
      // fallback: per-step launches (previous verified path)
      for (int t = c0; t < c0 + Tc; ++t)
        scan_step3<<<512, 256, 0, stream>>>(
            A_ws, t - c0, Tc, Ubf, wx, Vb,
            hbuf + (t & 1) * 8192, hbuf + ((t + 1) & 1) * 8192,
            cws, out, t);
    }
  }
}